// Round 6
// baseline (111.723 us; speedup 1.0000x reference)
//
#include <hip/hip_runtime.h>
#include <hip/hip_fp16.h>

// DeformConv3d fixed geometry:
// x: (2,32,24,24,24) f32, offset: (2,81,24,24,24) f32,
// weight: (64,32,3,3,3) f32, bias: (64,) f32 -> out: (2,64,24,24,24) f32
//
// LDS-free fused design:
//  prep: (a) x -> xT f16 channel-last [b][voxel][32c] (LDS transpose)
//        (b) weight -> f16 MFMA A-fragments, K reordered k'=kstep*32+c.
//  main: 256 thr (4 waves), each wave owns 16 positions, NO LDS/sync.
//        Per k-tap: lane (p=lane&15, q=lane>>4) trilinear-gathers channels
//        8q..8q+7 of its position -> that register IS the MFMA B-fragment.
//        4x mfma_f32_16x16x32_f16 (one per o-tile) reuse it for all 64 Cout.
//        Quad line-merge: lanes {l,l+16,l+32,l+48} read 4 consecutive 16B
//        chunks of one 64B corner line.

constexpr int B   = 2;
constexpr int C   = 32;
constexpr int D   = 24, H = 24, W = 24;
constexpr int CO  = 64;
constexpr int KN  = 27;
constexpr int DHW = D * H * W;        // 13824
constexpr int N   = DHW;
constexpr int CK  = C * KN;           // 864

constexpr int TPB_MAIN = 256;                      // 4 waves, 64 pos/block
constexpr int NBLK     = (B * N) / 64;             // 432

constexpr int PREPX_BLKS = (B * DHW) / 256;  // 108
constexpr int PREPW_BLKS = (CO * CK) / 256;  // 216

using h8v   = __attribute__((ext_vector_type(8))) _Float16;
using f32x4 = __attribute__((ext_vector_type(4))) float;

__device__ __forceinline__ h8v splat8(float w) {
    const _Float16 h = (_Float16)w;
    h8v r;
    #pragma unroll
    for (int i = 0; i < 8; ++i) r[i] = h;
    return r;
}

__device__ __forceinline__ unsigned pack2h(float a, float b) {
    const _Float16 ha = (_Float16)a, hb = (_Float16)b;
    unsigned short ua, ub;
    __builtin_memcpy(&ua, &ha, 2);
    __builtin_memcpy(&ub, &hb, 2);
    return (unsigned)ua | ((unsigned)ub << 16);
}

// ---- fused prep ----
__global__ __launch_bounds__(256)
void prep_fused(const float* __restrict__ x, const float* __restrict__ wgt,
                _Float16* __restrict__ xT, _Float16* __restrict__ wp) {
    const int bid = blockIdx.x;
    if (bid < PREPX_BLKS) {
        // transpose tile: 256 voxels x 32 channels; rows of 21 u32 (odd
        // stride -> conflict-free).
        __shared__ unsigned s_t[256 * 21];
        const int tid = threadIdx.x;
        const int v0  = bid * 256;
        const int b   = (v0 >= DHW) ? 1 : 0;
        const int vox = (v0 - b * DHW) + tid;
        const float* xb = x + (size_t)(b * C) * DHW + vox;
        #pragma unroll
        for (int c2 = 0; c2 < 16; ++c2) {
            const float f0 = xb[(size_t)(2 * c2)     * DHW];
            const float f1 = xb[(size_t)(2 * c2 + 1) * DHW];
            s_t[tid * 21 + c2] = pack2h(f0, f1);
        }
        __syncthreads();
        unsigned r[16];
        #pragma unroll
        for (int j = 0; j < 16; ++j) r[j] = s_t[tid * 21 + j];
        int4* dst = reinterpret_cast<int4*>(xT + ((size_t)(v0 + tid)) * 32);
        dst[0] = make_int4(r[0],  r[1],  r[2],  r[3]);
        dst[1] = make_int4(r[4],  r[5],  r[6],  r[7]);
        dst[2] = make_int4(r[8],  r[9],  r[10], r[11]);
        dst[3] = make_int4(r[12], r[13], r[14], r[15]);
    } else {
        // weight f32 -> f16 A-fragments:
        // elem idx = ((otile*27 + kstep)*64 + lane)*8 + j
        //   o = otile*16 + (lane&15), c = 8*(lane>>4) + j
        const int idx   = (bid - PREPX_BLKS) * 256 + threadIdx.x;
        const int j     = idx & 7;
        const int lane  = (idx >> 3) & 63;
        const int t     = idx >> 9;
        const int otile = t / 27;
        const int kstep = t - otile * 27;
        const int o     = otile * 16 + (lane & 15);
        const int c     = 8 * (lane >> 4) + j;
        wp[idx] = (_Float16)wgt[(size_t)o * CK + c * KN + kstep];
    }
}

// ---- main fused kernel: gather-to-B-fragment, no LDS ----
__global__ __launch_bounds__(TPB_MAIN)
void deform_main(const float* __restrict__ off,
                 const _Float16* __restrict__ xT,
                 const _Float16* __restrict__ wp,
                 const float* __restrict__ bias,
                 float* __restrict__ out) {
    const int tid  = threadIdx.x;
    const int lane = tid & 63;
    const int wv   = tid >> 6;                       // 0..3
    const int p    = lane & 15;                      // position within wave
    const int q    = lane >> 4;                      // channel chunk 0..3

    const int gp = blockIdx.x * 64 + wv * 16 + p;    // global (b,n); 64 | N
    const int b  = (gp >= N) ? 1 : 0;
    const int n  = gp - b * N;
    const int oz = n / 576;
    const int rr = n - oz * 576;
    const int oy = rr / 24;
    const int ox = rr - oy * 24;

    const float* offb  = off + (size_t)(b * 81) * N + n;
    const h8v*   xbase = reinterpret_cast<const h8v*>(xT) + (size_t)b * DHW * 4;
    const h8v*   wbase = reinterpret_cast<const h8v*>(wp);

    f32x4 acc[4];
    #pragma unroll
    for (int ot = 0; ot < 4; ++ot) acc[ot] = (f32x4){0.f, 0.f, 0.f, 0.f};

    #pragma unroll 1
    for (int ks = 0; ks < KN; ++ks) {
        const int kz = ks / 9;
        const int kr = ks - kz * 9;
        const int ky = kr / 3;
        const int kx = kr - ky * 3;

        const float offz = offb[(size_t)(ks * 3 + 0) * N];
        const float offy = offb[(size_t)(ks * 3 + 1) * N];
        const float offx = offb[(size_t)(ks * 3 + 2) * N];

        // A-fragments for this k-step (independent of gather; in flight early)
        h8v afr[4];
        #pragma unroll
        for (int ot = 0; ot < 4; ++ot)
            afr[ot] = wbase[(ot * 27 + ks) * 64 + lane];

        const float z  = (float)(oz - 1 + kz) + offz;
        const float y  = (float)(oy - 1 + ky) + offy;
        const float xx = (float)(ox - 1 + kx) + offx;
        const float zf = floorf(z), yf = floorf(y), xf = floorf(xx);
        const float fz = z - zf, fy = y - yf, fx = xx - xf;
        const int z0 = (int)zf, y0 = (int)yf, x0 = (int)xf;

        int   cidx[8];
        float cw[8];
        #pragma unroll
        for (int cr = 0; cr < 8; ++cr) {
            const int cz = cr >> 2, cy = (cr >> 1) & 1, cx = cr & 1;
            const int iz = z0 + cz, iy = y0 + cy, ix = x0 + cx;
            const bool vd = ((unsigned)iz < (unsigned)D) &&
                            ((unsigned)iy < (unsigned)H) &&
                            ((unsigned)ix < (unsigned)W);
            const int izc = min(max(iz, 0), D - 1);
            const int iyc = min(max(iy, 0), H - 1);
            const int ixc = min(max(ix, 0), W - 1);
            cidx[cr] = (izc * H + iyc) * W + ixc;
            const float wz = cz ? fz : 1.0f - fz;
            const float wy = cy ? fy : 1.0f - fy;
            const float wx = cx ? fx : 1.0f - fx;
            cw[cr] = vd ? (wz * wy * wx) : 0.0f;
        }

        // gather chunk q of all 8 corners; quad covers one 64B line/corner
        h8v v[8];
        #pragma unroll
        for (int cr = 0; cr < 8; ++cr)
            v[cr] = xbase[(size_t)cidx[cr] * 4 + q];

        h8v bfr = splat8(0.0f);
        #pragma unroll
        for (int cr = 0; cr < 8; ++cr)
            bfr += v[cr] * splat8(cw[cr]);

        // bfr IS the B-fragment: B[ks*32 + 8q+j][p]
        #pragma unroll
        for (int ot = 0; ot < 4; ++ot)
            acc[ot] = __builtin_amdgcn_mfma_f32_16x16x32_f16(afr[ot], bfr,
                                                             acc[ot], 0, 0, 0);
    }

    // C/D: col = lane&15 = p, row = q*4 + r (o within tile)
    #pragma unroll
    for (int ot = 0; ot < 4; ++ot) {
        #pragma unroll
        for (int r = 0; r < 4; ++r) {
            const int o = ot * 16 + q * 4 + r;
            out[((size_t)(b * CO + o)) * N + n] = acc[ot][r] + bias[o];
        }
    }
}

extern "C" void kernel_launch(void* const* d_in, const int* in_sizes, int n_in,
                              void* d_out, int out_size, void* d_ws, size_t ws_size,
                              hipStream_t stream) {
    const float* x    = (const float*)d_in[0];
    const float* off  = (const float*)d_in[1];
    const float* wgt  = (const float*)d_in[2];
    const float* bias = (const float*)d_in[3];
    float* out = (float*)d_out;

    _Float16* xT = (_Float16*)d_ws;                        // 1,769,472 B
    _Float16* wp = (_Float16*)((char*)d_ws + 1769472);     //   110,592 B

    prep_fused<<<PREPX_BLKS + PREPW_BLKS, 256, 0, stream>>>(x, wgt, xT, wp);
    deform_main<<<NBLK, TPB_MAIN, 0, stream>>>(off, xT, wp, bias, out);
}

// Round 7
// 107.213 us; speedup vs baseline: 1.0421x; 1.0421x over previous
//
#include <hip/hip_runtime.h>
#include <hip/hip_fp16.h>

// DeformConv3d fixed geometry:
// x: (2,32,24,24,24) f32, offset: (2,81,24,24,24) f32,
// weight: (64,32,3,3,3) f32, bias: (64,) f32 -> out: (2,64,24,24,24) f32
//
// K-split LDS-free design (r6: occupancy was the limiter, 432 blocks):
//  prep: (a) x -> xT f16 channel-last [b][voxel][32c] (LDS transpose)
//        (b) weight -> f16 MFMA A-fragments, K reordered k'=kstep*32+c.
//  main: 1728 blocks x 256 thr. All 4 waves share the SAME 16 positions;
//        K taps split {7,7,7,6} across waves (MFMA linear in K).
//        Per tap: lane (p=lane&15, q=lane>>4) trilinear-gathers channels
//        8q..8q+7 -> register IS the MFMA B-fragment; 4 MFMAs (o-tiles).
//        Offsets double-buffered in regs (prefetch k+1 under k's gather).
//        Epilogue: waves 1-3 dump acc to LDS, wave 0 reduces + stores.

constexpr int B   = 2;
constexpr int C   = 32;
constexpr int D   = 24, H = 24, W = 24;
constexpr int CO  = 64;
constexpr int KN  = 27;
constexpr int DHW = D * H * W;        // 13824
constexpr int N   = DHW;
constexpr int CK  = C * KN;           // 864

constexpr int TPB_MAIN = 256;              // 4 waves, 16 positions/block
constexpr int NBLK     = (B * N) / 16;     // 1728

constexpr int PREPX_BLKS = (B * DHW) / 256;  // 108
constexpr int PREPW_BLKS = (CO * CK) / 256;  // 216

using h8v   = __attribute__((ext_vector_type(8))) _Float16;
using f32x4 = __attribute__((ext_vector_type(4))) float;

__device__ __forceinline__ h8v splat8(float w) {
    const _Float16 h = (_Float16)w;
    h8v r;
    #pragma unroll
    for (int i = 0; i < 8; ++i) r[i] = h;
    return r;
}

__device__ __forceinline__ unsigned pack2h(float a, float b) {
    const _Float16 ha = (_Float16)a, hb = (_Float16)b;
    unsigned short ua, ub;
    __builtin_memcpy(&ua, &ha, 2);
    __builtin_memcpy(&ub, &hb, 2);
    return (unsigned)ua | ((unsigned)ub << 16);
}

// ---- fused prep ----
__global__ __launch_bounds__(256)
void prep_fused(const float* __restrict__ x, const float* __restrict__ wgt,
                _Float16* __restrict__ xT, _Float16* __restrict__ wp) {
    const int bid = blockIdx.x;
    if (bid < PREPX_BLKS) {
        // transpose tile: 256 voxels x 32 channels; rows of 21 u32 (odd
        // stride -> conflict-free).
        __shared__ unsigned s_t[256 * 21];
        const int tid = threadIdx.x;
        const int v0  = bid * 256;
        const int b   = (v0 >= DHW) ? 1 : 0;
        const int vox = (v0 - b * DHW) + tid;
        const float* xb = x + (size_t)(b * C) * DHW + vox;
        #pragma unroll
        for (int c2 = 0; c2 < 16; ++c2) {
            const float f0 = xb[(size_t)(2 * c2)     * DHW];
            const float f1 = xb[(size_t)(2 * c2 + 1) * DHW];
            s_t[tid * 21 + c2] = pack2h(f0, f1);
        }
        __syncthreads();
        unsigned r[16];
        #pragma unroll
        for (int j = 0; j < 16; ++j) r[j] = s_t[tid * 21 + j];
        int4* dst = reinterpret_cast<int4*>(xT + ((size_t)(v0 + tid)) * 32);
        dst[0] = make_int4(r[0],  r[1],  r[2],  r[3]);
        dst[1] = make_int4(r[4],  r[5],  r[6],  r[7]);
        dst[2] = make_int4(r[8],  r[9],  r[10], r[11]);
        dst[3] = make_int4(r[12], r[13], r[14], r[15]);
    } else {
        // weight f32 -> f16 A-fragments:
        // elem idx = ((otile*27 + kstep)*64 + lane)*8 + j
        //   o = otile*16 + (lane&15), c = 8*(lane>>4) + j
        const int idx   = (bid - PREPX_BLKS) * 256 + threadIdx.x;
        const int j     = idx & 7;
        const int lane  = (idx >> 3) & 63;
        const int t     = idx >> 9;
        const int otile = t / 27;
        const int kstep = t - otile * 27;
        const int o     = otile * 16 + (lane & 15);
        const int c     = 8 * (lane >> 4) + j;
        wp[idx] = (_Float16)wgt[(size_t)o * CK + c * KN + kstep];
    }
}

// ---- main fused kernel: K-split gather-to-B-fragment ----
__global__ __launch_bounds__(TPB_MAIN)
void deform_main(const float* __restrict__ off,
                 const _Float16* __restrict__ xT,
                 const _Float16* __restrict__ wp,
                 const float* __restrict__ bias,
                 float* __restrict__ out) {
    __shared__ float4 s_red[3 * 64 * 4];             // 12 KB

    const int tid  = threadIdx.x;
    const int lane = tid & 63;
    const int wv   = tid >> 6;                       // 0..3
    const int p    = lane & 15;                      // position within block
    const int q    = lane >> 4;                      // channel chunk 0..3

    const int gp = blockIdx.x * 16 + p;              // global (b,n); 16 | N
    const int b  = (gp >= N) ? 1 : 0;
    const int n  = gp - b * N;
    const int oz = n / 576;
    const int rr = n - oz * 576;
    const int oy = rr / 24;
    const int ox = rr - oy * 24;

    const float* offb  = off + (size_t)(b * 81) * N + n;
    const h8v*   xbase = reinterpret_cast<const h8v*>(xT) + (size_t)b * DHW * 4;
    const h8v*   wbase = reinterpret_cast<const h8v*>(wp);

    // K ranges per wave: {0-6, 7-13, 14-20, 21-26}
    const int k0 = wv * 7;
    const int k1 = (wv == 3) ? 27 : (k0 + 7);

    f32x4 acc[4];
    #pragma unroll
    for (int ot = 0; ot < 4; ++ot) acc[ot] = (f32x4){0.f, 0.f, 0.f, 0.f};

    // prefetch offsets for first tap
    float offz = offb[(size_t)(k0 * 3 + 0) * N];
    float offy = offb[(size_t)(k0 * 3 + 1) * N];
    float offx = offb[(size_t)(k0 * 3 + 2) * N];

    #pragma unroll 1
    for (int ks = k0; ks < k1; ++ks) {
        // prefetch next tap's offsets (clamped; overlaps this tap's gather)
        const int kn = (ks + 1 < k1) ? (ks + 1) : ks;
        const float nfz = offb[(size_t)(kn * 3 + 0) * N];
        const float nfy = offb[(size_t)(kn * 3 + 1) * N];
        const float nfx = offb[(size_t)(kn * 3 + 2) * N];

        const int kz = ks / 9;
        const int kr = ks - kz * 9;
        const int ky = kr / 3;
        const int kx = kr - ky * 3;

        // A-fragments for this k-step (independent; in flight early)
        h8v afr[4];
        #pragma unroll
        for (int ot = 0; ot < 4; ++ot)
            afr[ot] = wbase[(ot * 27 + ks) * 64 + lane];

        const float z  = (float)(oz - 1 + kz) + offz;
        const float y  = (float)(oy - 1 + ky) + offy;
        const float xx = (float)(ox - 1 + kx) + offx;
        const float zf = floorf(z), yf = floorf(y), xf = floorf(xx);
        const float fz = z - zf, fy = y - yf, fx = xx - xf;
        const int z0 = (int)zf, y0 = (int)yf, x0 = (int)xf;

        int   cidx[8];
        float cw[8];
        #pragma unroll
        for (int cr = 0; cr < 8; ++cr) {
            const int cz = cr >> 2, cy = (cr >> 1) & 1, cx = cr & 1;
            const int iz = z0 + cz, iy = y0 + cy, ix = x0 + cx;
            const bool vd = ((unsigned)iz < (unsigned)D) &&
                            ((unsigned)iy < (unsigned)H) &&
                            ((unsigned)ix < (unsigned)W);
            const int izc = min(max(iz, 0), D - 1);
            const int iyc = min(max(iy, 0), H - 1);
            const int ixc = min(max(ix, 0), W - 1);
            cidx[cr] = (izc * H + iyc) * W + ixc;
            const float wz = cz ? fz : 1.0f - fz;
            const float wy = cy ? fy : 1.0f - fy;
            const float wx = cx ? fx : 1.0f - fx;
            cw[cr] = vd ? (wz * wy * wx) : 0.0f;
        }

        // gather chunk q of all 8 corners; quad covers one 64B line/corner
        h8v v[8];
        #pragma unroll
        for (int cr = 0; cr < 8; ++cr)
            v[cr] = xbase[(size_t)cidx[cr] * 4 + q];

        h8v bfr = splat8(0.0f);
        #pragma unroll
        for (int cr = 0; cr < 8; ++cr)
            bfr += v[cr] * splat8(cw[cr]);

        // bfr IS the B-fragment: B[ks*32 + 8q+j][p]
        #pragma unroll
        for (int ot = 0; ot < 4; ++ot)
            acc[ot] = __builtin_amdgcn_mfma_f32_16x16x32_f16(afr[ot], bfr,
                                                             acc[ot], 0, 0, 0);

        offz = nfz; offy = nfy; offx = nfx;
    }

    // ---- cross-wave K reduction ----
    if (wv > 0) {
        float4* dst = &s_red[((wv - 1) * 64 + lane) * 4];
        #pragma unroll
        for (int ot = 0; ot < 4; ++ot) {
            dst[ot] = make_float4(acc[ot][0], acc[ot][1], acc[ot][2], acc[ot][3]);
        }
    }
    __syncthreads();
    if (wv == 0) {
        #pragma unroll
        for (int w = 0; w < 3; ++w) {
            const float4* src = &s_red[(w * 64 + lane) * 4];
            #pragma unroll
            for (int ot = 0; ot < 4; ++ot) {
                const float4 t = src[ot];
                acc[ot][0] += t.x; acc[ot][1] += t.y;
                acc[ot][2] += t.z; acc[ot][3] += t.w;
            }
        }
        // C/D: col = lane&15 = p, row = q*4 + r (o within tile)
        #pragma unroll
        for (int ot = 0; ot < 4; ++ot) {
            #pragma unroll
            for (int r = 0; r < 4; ++r) {
                const int o = ot * 16 + q * 4 + r;
                out[((size_t)(b * CO + o)) * N + n] = acc[ot][r] + bias[o];
            }
        }
    }
}

extern "C" void kernel_launch(void* const* d_in, const int* in_sizes, int n_in,
                              void* d_out, int out_size, void* d_ws, size_t ws_size,
                              hipStream_t stream) {
    const float* x    = (const float*)d_in[0];
    const float* off  = (const float*)d_in[1];
    const float* wgt  = (const float*)d_in[2];
    const float* bias = (const float*)d_in[3];
    float* out = (float*)d_out;

    _Float16* xT = (_Float16*)d_ws;                        // 1,769,472 B
    _Float16* wp = (_Float16*)((char*)d_ws + 1769472);     //   110,592 B

    prep_fused<<<PREPX_BLKS + PREPW_BLKS, 256, 0, stream>>>(x, wgt, xT, wp);
    deform_main<<<NBLK, TPB_MAIN, 0, stream>>>(off, xT, wp, bias, out);
}

// Round 9
// 104.685 us; speedup vs baseline: 1.0672x; 1.0242x over previous
//
#include <hip/hip_runtime.h>
#include <hip/hip_fp16.h>

// DeformConv3d fixed geometry:
// x: (2,32,24,24,24) f32, offset: (2,81,24,24,24) f32,
// weight: (64,32,3,3,3) f32, bias: (64,) f32 -> out: (2,64,24,24,24) f32
//
// r8: LDS-staged gather (r3-r7 invariant 47us = per-lane scattered VMEM).
//  prep: (a) x -> xT f16 channel-last [b][voxel][32c] (LDS transpose)
//        (b) weight -> f16 MFMA A-fragments, K reordered k'=kstep*32+c.
//  main: 432 blocks (2 batches x 6^3 tiles of 4x4x4 outputs), 256 thr.
//        Stage 10^3 voxel neighborhood (margin -3..+6, pre-clamped) as
//        f16 channel-last in 64000 B LDS, chunk-swizzled ((c+v)&3) to
//        spread banks. Gather per tap from LDS (32 banks in parallel);
//        ~13% out-of-window taps fall back to exec-masked global loads.
//        Wave wv = pz-plane: 16 positions, full K, 4 MFMAs/tap (o-tiles).

constexpr int B   = 2;
constexpr int C   = 32;
constexpr int D   = 24, H = 24, W = 24;
constexpr int CO  = 64;
constexpr int KN  = 27;
constexpr int DHW = D * H * W;        // 13824
constexpr int N   = DHW;
constexpr int CK  = C * KN;           // 864

constexpr int LD   = 10;              // staged extent per dim
constexpr int MB   = 3;               // margin below tile origin
constexpr int NVOX = LD * LD * LD;    // 1000 voxels -> 64000 B LDS

constexpr int TPB_MAIN = 256;         // 4 waves; wave = pz plane (16 pos)
constexpr int NBLK     = B * 6 * 6 * 6;   // 432

constexpr int PREPX_BLKS = (B * DHW) / 256;  // 108
constexpr int PREPW_BLKS = (CO * CK) / 256;  // 216

using h8v   = __attribute__((ext_vector_type(8))) _Float16;
using f32x4 = __attribute__((ext_vector_type(4))) float;

__device__ __forceinline__ h8v splat8(float w) {
    const _Float16 h = (_Float16)w;
    h8v r;
    #pragma unroll
    for (int i = 0; i < 8; ++i) r[i] = h;
    return r;
}

__device__ __forceinline__ unsigned pack2h(float a, float b) {
    const _Float16 ha = (_Float16)a, hb = (_Float16)b;
    unsigned short ua, ub;
    __builtin_memcpy(&ua, &ha, 2);
    __builtin_memcpy(&ub, &hb, 2);
    return (unsigned)ua | ((unsigned)ub << 16);
}

// ---- fused prep ----
__global__ __launch_bounds__(256)
void prep_fused(const float* __restrict__ x, const float* __restrict__ wgt,
                _Float16* __restrict__ xT, _Float16* __restrict__ wp) {
    const int bid = blockIdx.x;
    if (bid < PREPX_BLKS) {
        // transpose tile: 256 voxels x 32 channels; rows of 21 u32 (odd
        // stride -> conflict-free).
        __shared__ unsigned s_t[256 * 21];
        const int tid = threadIdx.x;
        const int v0  = bid * 256;
        const int b   = (v0 >= DHW) ? 1 : 0;
        const int vox = (v0 - b * DHW) + tid;
        const float* xb = x + (size_t)(b * C) * DHW + vox;
        #pragma unroll
        for (int c2 = 0; c2 < 16; ++c2) {
            const float f0 = xb[(size_t)(2 * c2)     * DHW];
            const float f1 = xb[(size_t)(2 * c2 + 1) * DHW];
            s_t[tid * 21 + c2] = pack2h(f0, f1);
        }
        __syncthreads();
        unsigned r[16];
        #pragma unroll
        for (int j = 0; j < 16; ++j) r[j] = s_t[tid * 21 + j];
        int4* dst = reinterpret_cast<int4*>(xT + ((size_t)(v0 + tid)) * 32);
        dst[0] = make_int4(r[0],  r[1],  r[2],  r[3]);
        dst[1] = make_int4(r[4],  r[5],  r[6],  r[7]);
        dst[2] = make_int4(r[8],  r[9],  r[10], r[11]);
        dst[3] = make_int4(r[12], r[13], r[14], r[15]);
    } else {
        // weight f32 -> f16 A-fragments:
        // elem idx = ((otile*27 + kstep)*64 + lane)*8 + j
        //   o = otile*16 + (lane&15), c = 8*(lane>>4) + j
        const int idx   = (bid - PREPX_BLKS) * 256 + threadIdx.x;
        const int j     = idx & 7;
        const int lane  = (idx >> 3) & 63;
        const int t     = idx >> 9;
        const int otile = t / 27;
        const int kstep = t - otile * 27;
        const int o     = otile * 16 + (lane & 15);
        const int c     = 8 * (lane >> 4) + j;
        wp[idx] = (_Float16)wgt[(size_t)o * CK + c * KN + kstep];
    }
}

__device__ __forceinline__ int clamp0(int v, int hi) {
    return min(max(v, 0), hi);
}

// ---- main: LDS-staged gather + MFMA ----
__global__ __launch_bounds__(TPB_MAIN)
void deform_main(const float* __restrict__ off,
                 const _Float16* __restrict__ xT,
                 const _Float16* __restrict__ wp,
                 const float* __restrict__ bias,
                 float* __restrict__ out) {
    __shared__ h8v s_x[NVOX * 4];                    // 64000 B

    const int tid  = threadIdx.x;
    const int lane = tid & 63;
    const int wv   = tid >> 6;                       // 0..3 = pz plane
    const int p    = lane & 15;                      // position within plane
    const int q    = lane >> 4;                      // channel chunk 0..3

    int t = blockIdx.x;
    int b = 0;
    if (t >= 216) { b = 1; t -= 216; }
    const int tz = t / 36;
    const int rt = t - tz * 36;
    const int ty = rt / 6;
    const int tx = rt - ty * 6;
    const int oz0 = tz * 4, oy0 = ty * 4, ox0 = tx * 4;
    const int tbz = oz0 - MB, tby = oy0 - MB, tbx = ox0 - MB;

    const h8v* xbase = reinterpret_cast<const h8v*>(xT) + (size_t)b * DHW * 4;

    // ---- stage 10^3 neighborhood, pre-clamped, chunk-swizzled ----
    for (int i = tid; i < NVOX * 4; i += TPB_MAIN) {
        const int v  = i >> 2;
        const int c  = i & 3;
        const int vz = v / 100;
        const int vr = v - vz * 100;
        const int vy = vr / 10;
        const int vx = vr - vy * 10;
        const int gz = clamp0(tbz + vz, D - 1);
        const int gy = clamp0(tby + vy, H - 1);
        const int gx = clamp0(tbx + vx, W - 1);
        const int gvox = (gz * H + gy) * W + gx;
        s_x[v * 4 + ((c + v) & 3)] = xbase[(size_t)gvox * 4 + c];
    }
    __syncthreads();

    // ---- per-wave positions ----
    const int pz = wv, py = p >> 2, px = p & 3;
    const int oz = oz0 + pz, oy = oy0 + py, ox = ox0 + px;
    const int n  = (oz * H + oy) * W + ox;
    const float* offp  = off + (size_t)(b * 81) * N + n;
    const h8v*   wbase = reinterpret_cast<const h8v*>(wp);

    f32x4 acc[4];
    #pragma unroll
    for (int ot = 0; ot < 4; ++ot) acc[ot] = (f32x4){0.f, 0.f, 0.f, 0.f};

    #pragma unroll 1
    for (int ks = 0; ks < KN; ++ks) {
        const int kz = ks / 9;
        const int kr = ks - kz * 9;
        const int ky = kr / 3;
        const int kx = kr - ky * 3;

        const float offz = offp[(size_t)(ks * 3 + 0) * N];
        const float offy = offp[(size_t)(ks * 3 + 1) * N];
        const float offx = offp[(size_t)(ks * 3 + 2) * N];

        // A-fragments (coalesced, L1/L2-hot)
        h8v afr[4];
        #pragma unroll
        for (int ot = 0; ot < 4; ++ot)
            afr[ot] = wbase[(ot * 27 + ks) * 64 + lane];

        const float z  = (float)(oz - 1 + kz) + offz;
        const float y  = (float)(oy - 1 + ky) + offy;
        const float xx = (float)(ox - 1 + kx) + offx;
        const float zf = floorf(z), yf = floorf(y), xf = floorf(xx);
        const float fz = z - zf, fy = y - yf, fx = xx - xf;
        const int z0 = (int)zf, y0 = (int)yf, x0 = (int)xf;

        // trilinear weights with validity zeroing (reference semantics)
        float cw[8];
        #pragma unroll
        for (int cr = 0; cr < 8; ++cr) {
            const int cz = cr >> 2, cy = (cr >> 1) & 1, cx = cr & 1;
            const int iz = z0 + cz, iy = y0 + cy, ix = x0 + cx;
            const bool vd = ((unsigned)iz < (unsigned)D) &&
                            ((unsigned)iy < (unsigned)H) &&
                            ((unsigned)ix < (unsigned)W);
            const float wz = cz ? fz : 1.0f - fz;
            const float wy = cy ? fy : 1.0f - fy;
            const float wx = cx ? fx : 1.0f - fx;
            cw[cr] = vd ? (wz * wy * wx) : 0.0f;
        }

        // window test: corners z0..z0+1 must lie in [tb, tb+LD)
        const int rz = z0 - tbz, ry = y0 - tby, rx = x0 - tbx;
        const bool in = ((unsigned)rz < (unsigned)(LD - 1)) &&
                        ((unsigned)ry < (unsigned)(LD - 1)) &&
                        ((unsigned)rx < (unsigned)(LD - 1));

        h8v v8[8];
        if (in) {
            // staged slots are pre-clamped -> no index clamping needed
            const int rv0 = (rz * LD + ry) * LD + rx;
            #pragma unroll
            for (int cr = 0; cr < 8; ++cr) {
                const int rv = rv0 + (cr >> 2) * 100 + ((cr >> 1) & 1) * 10
                             + (cr & 1);
                v8[cr] = s_x[rv * 4 + ((q + rv) & 3)];
            }
        }
        if (!in) {
            // rare fallback: clamped scattered global loads
            #pragma unroll
            for (int cr = 0; cr < 8; ++cr) {
                const int cz = cr >> 2, cy = (cr >> 1) & 1, cx = cr & 1;
                const int izc = clamp0(z0 + cz, D - 1);
                const int iyc = clamp0(y0 + cy, H - 1);
                const int ixc = clamp0(x0 + cx, W - 1);
                const int gvox = (izc * H + iyc) * W + ixc;
                v8[cr] = xbase[(size_t)gvox * 4 + q];
            }
        }

        h8v bfr = splat8(0.0f);
        #pragma unroll
        for (int cr = 0; cr < 8; ++cr)
            bfr += v8[cr] * splat8(cw[cr]);

        // bfr IS the B-fragment: B[ks*32 + 8q+j][col=p]
        #pragma unroll
        for (int ot = 0; ot < 4; ++ot)
            acc[ot] = __builtin_amdgcn_mfma_f32_16x16x32_f16(afr[ot], bfr,
                                                             acc[ot], 0, 0, 0);
    }

    // C/D: col = lane&15 = p, row = q*4 + r (o within tile)
    #pragma unroll
    for (int ot = 0; ot < 4; ++ot) {
        #pragma unroll
        for (int r = 0; r < 4; ++r) {
            const int o = ot * 16 + q * 4 + r;
            out[((size_t)(b * CO + o)) * N + n] = acc[ot][r] + bias[o];
        }
    }
}

extern "C" void kernel_launch(void* const* d_in, const int* in_sizes, int n_in,
                              void* d_out, int out_size, void* d_ws, size_t ws_size,
                              hipStream_t stream) {
    const float* x    = (const float*)d_in[0];
    const float* off  = (const float*)d_in[1];
    const float* wgt  = (const float*)d_in[2];
    const float* bias = (const float*)d_in[3];
    float* out = (float*)d_out;

    _Float16* xT = (_Float16*)d_ws;                        // 1,769,472 B
    _Float16* wp = (_Float16*)((char*)d_ws + 1769472);     //   110,592 B

    prep_fused<<<PREPX_BLKS + PREPW_BLKS, 256, 0, stream>>>(x, wgt, xT, wp);
    deform_main<<<NBLK, TPB_MAIN, 0, stream>>>(off, xT, wp, bias, out);
}

// Round 10
// 100.744 us; speedup vs baseline: 1.1090x; 1.0391x over previous
//
#include <hip/hip_runtime.h>
#include <hip/hip_fp16.h>

// DeformConv3d fixed geometry:
// x: (2,32,24,24,24) f32, offset: (2,81,24,24,24) f32,
// weight: (64,32,3,3,3) f32, bias: (64,) f32 -> out: (2,64,24,24,24) f32
//
// r10 = r9 + overlap: tile 2x4x4 (32 pos), window 8x10x10 = 51.2 KB LDS
// -> 3 blocks/CU, 864 blocks, 4 waves = 2 pos-planes x K-split-2.
// XCD-bijective blockIdx swizzle for halo L2 reuse. launch_bounds(256,3).

constexpr int B   = 2;
constexpr int C   = 32;
constexpr int D   = 24, H = 24, W = 24;
constexpr int CO  = 64;
constexpr int KN  = 27;
constexpr int DHW = D * H * W;        // 13824
constexpr int N   = DHW;
constexpr int CK  = C * KN;           // 864

constexpr int TZ = 2, TY = 4, TX = 4;     // output tile
constexpr int LDZ = 8, LDY = 10, LDX = 10;
constexpr int NVOX = LDZ * LDY * LDX;     // 800 -> 51200 B LDS
constexpr int MBM  = 3;                   // margin below

constexpr int TPB_MAIN = 256;             // 4 waves: (pg, kh)
constexpr int NBLK     = B * 12 * 6 * 6;  // 864

constexpr int PREPX_BLKS = (B * DHW) / 256;  // 108
constexpr int PREPW_BLKS = (CO * CK) / 256;  // 216

using h8v   = __attribute__((ext_vector_type(8))) _Float16;
using f32x4 = __attribute__((ext_vector_type(4))) float;

__device__ __forceinline__ h8v splat8(float w) {
    const _Float16 h = (_Float16)w;
    h8v r;
    #pragma unroll
    for (int i = 0; i < 8; ++i) r[i] = h;
    return r;
}

__device__ __forceinline__ unsigned pack2h(float a, float b) {
    const _Float16 ha = (_Float16)a, hb = (_Float16)b;
    unsigned short ua, ub;
    __builtin_memcpy(&ua, &ha, 2);
    __builtin_memcpy(&ub, &hb, 2);
    return (unsigned)ua | ((unsigned)ub << 16);
}

// ---- fused prep (unchanged from r9) ----
__global__ __launch_bounds__(256)
void prep_fused(const float* __restrict__ x, const float* __restrict__ wgt,
                _Float16* __restrict__ xT, _Float16* __restrict__ wp) {
    const int bid = blockIdx.x;
    if (bid < PREPX_BLKS) {
        __shared__ unsigned s_t[256 * 21];
        const int tid = threadIdx.x;
        const int v0  = bid * 256;
        const int b   = (v0 >= DHW) ? 1 : 0;
        const int vox = (v0 - b * DHW) + tid;
        const float* xb = x + (size_t)(b * C) * DHW + vox;
        #pragma unroll
        for (int c2 = 0; c2 < 16; ++c2) {
            const float f0 = xb[(size_t)(2 * c2)     * DHW];
            const float f1 = xb[(size_t)(2 * c2 + 1) * DHW];
            s_t[tid * 21 + c2] = pack2h(f0, f1);
        }
        __syncthreads();
        unsigned r[16];
        #pragma unroll
        for (int j = 0; j < 16; ++j) r[j] = s_t[tid * 21 + j];
        int4* dst = reinterpret_cast<int4*>(xT + ((size_t)(v0 + tid)) * 32);
        dst[0] = make_int4(r[0],  r[1],  r[2],  r[3]);
        dst[1] = make_int4(r[4],  r[5],  r[6],  r[7]);
        dst[2] = make_int4(r[8],  r[9],  r[10], r[11]);
        dst[3] = make_int4(r[12], r[13], r[14], r[15]);
    } else {
        const int idx   = (bid - PREPX_BLKS) * 256 + threadIdx.x;
        const int j     = idx & 7;
        const int lane  = (idx >> 3) & 63;
        const int t     = idx >> 9;
        const int otile = t / 27;
        const int kstep = t - otile * 27;
        const int o     = otile * 16 + (lane & 15);
        const int c     = 8 * (lane >> 4) + j;
        wp[idx] = (_Float16)wgt[(size_t)o * CK + c * KN + kstep];
    }
}

__device__ __forceinline__ int clamp0(int v, int hi) {
    return min(max(v, 0), hi);
}

// ---- main: LDS-staged gather + MFMA, K-split, 3 blocks/CU ----
__global__ __launch_bounds__(TPB_MAIN, 3)
void deform_main(const float* __restrict__ off,
                 const _Float16* __restrict__ xT,
                 const _Float16* __restrict__ wp,
                 const float* __restrict__ bias,
                 float* __restrict__ out) {
    __shared__ h8v s_x[NVOX * 4];                    // 51200 B

    const int tid  = threadIdx.x;
    const int lane = tid & 63;
    const int wv   = tid >> 6;                       // 0..3
    const int pg   = wv >> 1;                        // pos-plane 0..1 (= pz)
    const int kh   = wv & 1;                         // K half
    const int p    = lane & 15;                      // position within plane
    const int q    = lane >> 4;                      // channel chunk 0..3

    // bijective XCD swizzle: 864 = 8 * 108; chunk per XCD, tx fastest inside
    const int bid = blockIdx.x;
    int t = (bid & 7) * 108 + (bid >> 3);
    int b = 0;
    if (t >= 432) { b = 1; t -= 432; }
    const int tz = t / 36;                           // 0..11
    const int rt = t - tz * 36;
    const int ty = rt / 6;
    const int tx = rt - ty * 6;
    const int oz0 = tz * TZ, oy0 = ty * TY, ox0 = tx * TX;
    const int tbz = oz0 - MBM, tby = oy0 - MBM, tbx = ox0 - MBM;

    const h8v* xbase = reinterpret_cast<const h8v*>(xT) + (size_t)b * DHW * 4;

    // ---- stage 8x10x10 neighborhood, pre-clamped, chunk-swizzled ----
    for (int i = tid; i < NVOX * 4; i += TPB_MAIN) {
        const int v  = i >> 2;
        const int c  = i & 3;
        const int vz = v / (LDY * LDX);
        const int vr = v - vz * (LDY * LDX);
        const int vy = vr / LDX;
        const int vx = vr - vy * LDX;
        const int gz = clamp0(tbz + vz, D - 1);
        const int gy = clamp0(tby + vy, H - 1);
        const int gx = clamp0(tbx + vx, W - 1);
        const int gvox = (gz * H + gy) * W + gx;
        s_x[v * 4 + ((c + v) & 3)] = xbase[(size_t)gvox * 4 + c];
    }
    __syncthreads();

    // ---- per-wave positions ----
    const int pz = pg, py = p >> 2, px = p & 3;
    const int oz = oz0 + pz, oy = oy0 + py, ox = ox0 + px;
    const int n  = (oz * H + oy) * W + ox;
    const float* offp  = off + (size_t)(b * 81) * N + n;
    const h8v*   wbase = reinterpret_cast<const h8v*>(wp);

    // K ranges: kh=0 -> 0..13, kh=1 -> 14..26
    const int k0 = kh ? 14 : 0;
    const int k1 = kh ? 27 : 14;

    f32x4 acc[4];
    #pragma unroll
    for (int ot = 0; ot < 4; ++ot) acc[ot] = (f32x4){0.f, 0.f, 0.f, 0.f};

    float offz = offp[(size_t)(k0 * 3 + 0) * N];
    float offy = offp[(size_t)(k0 * 3 + 1) * N];
    float offx = offp[(size_t)(k0 * 3 + 2) * N];

    #pragma unroll 1
    for (int ks = k0; ks < k1; ++ks) {
        const int kn = (ks + 1 < k1) ? (ks + 1) : ks;
        const float nfz = offp[(size_t)(kn * 3 + 0) * N];
        const float nfy = offp[(size_t)(kn * 3 + 1) * N];
        const float nfx = offp[(size_t)(kn * 3 + 2) * N];

        const int kz = ks / 9;
        const int kr = ks - kz * 9;
        const int ky = kr / 3;
        const int kx = kr - ky * 3;

        // A-fragments (coalesced, L2-hot)
        h8v afr[4];
        #pragma unroll
        for (int ot = 0; ot < 4; ++ot)
            afr[ot] = wbase[(ot * 27 + ks) * 64 + lane];

        const float z  = (float)(oz - 1 + kz) + offz;
        const float y  = (float)(oy - 1 + ky) + offy;
        const float xx = (float)(ox - 1 + kx) + offx;
        const float zf = floorf(z), yf = floorf(y), xf = floorf(xx);
        const float fz = z - zf, fy = y - yf, fx = xx - xf;
        const int z0 = (int)zf, y0 = (int)yf, x0 = (int)xf;

        float cw[8];
        #pragma unroll
        for (int cr = 0; cr < 8; ++cr) {
            const int cz = cr >> 2, cy = (cr >> 1) & 1, cx = cr & 1;
            const int iz = z0 + cz, iy = y0 + cy, ix = x0 + cx;
            const bool vd = ((unsigned)iz < (unsigned)D) &&
                            ((unsigned)iy < (unsigned)H) &&
                            ((unsigned)ix < (unsigned)W);
            const float wz = cz ? fz : 1.0f - fz;
            const float wy = cy ? fy : 1.0f - fy;
            const float wx = cx ? fx : 1.0f - fx;
            cw[cr] = vd ? (wz * wy * wx) : 0.0f;
        }

        // window test: corners must lie in [tb, tb+LD)
        const int rz = z0 - tbz, ry = y0 - tby, rx = x0 - tbx;
        const bool in = ((unsigned)rz < (unsigned)(LDZ - 1)) &&
                        ((unsigned)ry < (unsigned)(LDY - 1)) &&
                        ((unsigned)rx < (unsigned)(LDX - 1));

        h8v v8[8];
        if (in) {
            const int rv0 = (rz * LDY + ry) * LDX + rx;
            #pragma unroll
            for (int cr = 0; cr < 8; ++cr) {
                const int rv = rv0 + (cr >> 2) * (LDY * LDX)
                             + ((cr >> 1) & 1) * LDX + (cr & 1);
                v8[cr] = s_x[rv * 4 + ((q + rv) & 3)];
            }
        }
        if (!in) {
            #pragma unroll
            for (int cr = 0; cr < 8; ++cr) {
                const int cz = cr >> 2, cy = (cr >> 1) & 1, cx = cr & 1;
                const int izc = clamp0(z0 + cz, D - 1);
                const int iyc = clamp0(y0 + cy, H - 1);
                const int ixc = clamp0(x0 + cx, W - 1);
                const int gvox = (izc * H + iyc) * W + ixc;
                v8[cr] = xbase[(size_t)gvox * 4 + q];
            }
        }

        h8v bfr = splat8(0.0f);
        #pragma unroll
        for (int cr = 0; cr < 8; ++cr)
            bfr += v8[cr] * splat8(cw[cr]);

        // bfr IS the B-fragment: B[ks*32 + 8q+j][col=p]
        #pragma unroll
        for (int ot = 0; ot < 4; ++ot)
            acc[ot] = __builtin_amdgcn_mfma_f32_16x16x32_f16(afr[ot], bfr,
                                                             acc[ot], 0, 0, 0);

        offz = nfz; offy = nfy; offx = nfx;
    }

    // ---- cross-wave K reduction (reuse staging LDS) ----
    __syncthreads();
    float4* s_red = reinterpret_cast<float4*>(s_x);  // 8 KB used
    if (kh == 1) {
        float4* dst = &s_red[((size_t)pg * 64 + lane) * 4];
        #pragma unroll
        for (int ot = 0; ot < 4; ++ot)
            dst[ot] = make_float4(acc[ot][0], acc[ot][1], acc[ot][2], acc[ot][3]);
    }
    __syncthreads();
    if (kh == 0) {
        const float4* src = &s_red[((size_t)pg * 64 + lane) * 4];
        #pragma unroll
        for (int ot = 0; ot < 4; ++ot) {
            const float4 tv = src[ot];
            acc[ot][0] += tv.x; acc[ot][1] += tv.y;
            acc[ot][2] += tv.z; acc[ot][3] += tv.w;
        }
        // C/D: col = lane&15 = p, row = q*4 + r (o within tile)
        #pragma unroll
        for (int ot = 0; ot < 4; ++ot) {
            #pragma unroll
            for (int r = 0; r < 4; ++r) {
                const int o = ot * 16 + q * 4 + r;
                out[((size_t)(b * CO + o)) * N + n] = acc[ot][r] + bias[o];
            }
        }
    }
}

extern "C" void kernel_launch(void* const* d_in, const int* in_sizes, int n_in,
                              void* d_out, int out_size, void* d_ws, size_t ws_size,
                              hipStream_t stream) {
    const float* x    = (const float*)d_in[0];
    const float* off  = (const float*)d_in[1];
    const float* wgt  = (const float*)d_in[2];
    const float* bias = (const float*)d_in[3];
    float* out = (float*)d_out;

    _Float16* xT = (_Float16*)d_ws;                        // 1,769,472 B
    _Float16* wp = (_Float16*)((char*)d_ws + 1769472);     //   110,592 B

    prep_fused<<<PREPX_BLKS + PREPW_BLKS, 256, 0, stream>>>(x, wgt, xT, wp);
    deform_main<<<NBLK, TPB_MAIN, 0, stream>>>(off, xT, wp, bias, out);
}

// Round 11
// 100.168 us; speedup vs baseline: 1.1154x; 1.0058x over previous
//
#include <hip/hip_runtime.h>
#include <hip/hip_fp16.h>

// DeformConv3d fixed geometry:
// x: (2,32,24,24,24) f32, offset: (2,81,24,24,24) f32,
// weight: (64,32,3,3,3) f32, bias: (64,) f32 -> out: (2,64,24,24,24) f32
//
// r11: pre-resolved misses + branch-free k-loop.
//  Phase1: 864 (pos,tap) tasks -> cw8(f16x8), window idx, miss slot (LDS).
//  Phase2: compacted misses (E~46/block): lane-packed scattered gathers.
//  Phase3: k-loop = pure LDS (cw/meta + 8 window reads + masked miss
//          select) + prefetched A-frags + 4 MFMA. No globals in chain.

constexpr int B   = 2;
constexpr int C   = 32;
constexpr int D   = 24, H = 24, W = 24;
constexpr int CO  = 64;
constexpr int KN  = 27;
constexpr int DHW = D * H * W;        // 13824
constexpr int N   = DHW;
constexpr int CK  = C * KN;           // 864

constexpr int TZ = 2, TY = 4, TX = 4;     // output tile (32 pos)
constexpr int LDZ = 8, LDY = 10, LDX = 10;
constexpr int NVOX = LDZ * LDY * LDX;     // 800 -> 51200 B
constexpr int MBM  = 3;
constexpr int NPOS  = 32;
constexpr int NTASK = NPOS * KN;          // 864
constexpr int CAP   = 160;                // miss-list capacity

constexpr int TPB_MAIN = 256;
constexpr int NBLK     = B * 12 * 6 * 6;  // 864

constexpr int PREPX_BLKS = (B * DHW) / 256;  // 108
constexpr int PREPW_BLKS = (CO * CK) / 256;  // 216

using h8v   = __attribute__((ext_vector_type(8))) _Float16;
using f32x4 = __attribute__((ext_vector_type(4))) float;

__device__ __forceinline__ h8v splat8h(_Float16 h) {
    h8v r;
    #pragma unroll
    for (int i = 0; i < 8; ++i) r[i] = h;
    return r;
}

__device__ __forceinline__ unsigned pack2h(float a, float b) {
    const _Float16 ha = (_Float16)a, hb = (_Float16)b;
    unsigned short ua, ub;
    __builtin_memcpy(&ua, &ha, 2);
    __builtin_memcpy(&ub, &hb, 2);
    return (unsigned)ua | ((unsigned)ub << 16);
}

__device__ __forceinline__ int clamp0(int v, int hi) {
    return min(max(v, 0), hi);
}

// ---- fused prep (unchanged) ----
__global__ __launch_bounds__(256)
void prep_fused(const float* __restrict__ x, const float* __restrict__ wgt,
                _Float16* __restrict__ xT, _Float16* __restrict__ wp) {
    const int bid = blockIdx.x;
    if (bid < PREPX_BLKS) {
        __shared__ unsigned s_t[256 * 21];
        const int tid = threadIdx.x;
        const int v0  = bid * 256;
        const int b   = (v0 >= DHW) ? 1 : 0;
        const int vox = (v0 - b * DHW) + tid;
        const float* xb = x + (size_t)(b * C) * DHW + vox;
        #pragma unroll
        for (int c2 = 0; c2 < 16; ++c2) {
            const float f0 = xb[(size_t)(2 * c2)     * DHW];
            const float f1 = xb[(size_t)(2 * c2 + 1) * DHW];
            s_t[tid * 21 + c2] = pack2h(f0, f1);
        }
        __syncthreads();
        unsigned r[16];
        #pragma unroll
        for (int j = 0; j < 16; ++j) r[j] = s_t[tid * 21 + j];
        int4* dst = reinterpret_cast<int4*>(xT + ((size_t)(v0 + tid)) * 32);
        dst[0] = make_int4(r[0],  r[1],  r[2],  r[3]);
        dst[1] = make_int4(r[4],  r[5],  r[6],  r[7]);
        dst[2] = make_int4(r[8],  r[9],  r[10], r[11]);
        dst[3] = make_int4(r[12], r[13], r[14], r[15]);
    } else {
        const int idx   = (bid - PREPX_BLKS) * 256 + threadIdx.x;
        const int j     = idx & 7;
        const int lane  = (idx >> 3) & 63;
        const int t     = idx >> 9;
        const int otile = t / 27;
        const int kstep = t - otile * 27;
        const int o     = otile * 16 + (lane & 15);
        const int c     = 8 * (lane >> 4) + j;
        wp[idx] = (_Float16)wgt[(size_t)o * CK + c * KN + kstep];
    }
}

// ---- main ----
__global__ __launch_bounds__(TPB_MAIN, 2)
void deform_main(const float* __restrict__ off,
                 const _Float16* __restrict__ xT,
                 const _Float16* __restrict__ wp,
                 const float* __restrict__ bias,
                 float* __restrict__ out) {
    __shared__ h8v      s_win[NVOX * 4];   // 51200 B
    __shared__ h8v      s_cw [NTASK];      // 13824 B
    __shared__ unsigned s_meta[NTASK];     //  3456 B
    __shared__ h8v      s_mval[CAP * 4];   // 10240 B
    __shared__ unsigned short s_mlist[CAP];
    __shared__ int      s_cnt;

    const int tid  = threadIdx.x;
    const int lane = tid & 63;
    const int wv   = tid >> 6;
    const int pg   = wv >> 1;               // pos half (16 each)
    const int kh   = wv & 1;                // K half
    const int p    = lane & 15;
    const int q    = lane >> 4;

    // bijective XCD swizzle: 864 = 8 * 108
    const int bid = blockIdx.x;
    int t0 = (bid & 7) * 108 + (bid >> 3);
    int b = 0;
    if (t0 >= 432) { b = 1; t0 -= 432; }
    const int tz = t0 / 36;
    const int rt = t0 - tz * 36;
    const int ty = rt / 6;
    const int tx = rt - ty * 6;
    const int oz0 = tz * TZ, oy0 = ty * TY, ox0 = tx * TX;
    const int tbz = oz0 - MBM, tby = oy0 - MBM, tbx = ox0 - MBM;

    const h8v*   xbase = reinterpret_cast<const h8v*>(xT) + (size_t)b * DHW * 4;
    const float* offb  = off + (size_t)(b * 81) * N;
    const h8v*   wbase = reinterpret_cast<const h8v*>(wp);

    if (tid == 0) s_cnt = 0;
    __syncthreads();

    // ---- phase 0: stage window (pre-clamped, chunk-swizzled) ----
    for (int i = tid; i < NVOX * 4; i += TPB_MAIN) {
        const int v  = i >> 2;
        const int c  = i & 3;
        const int vz = v / (LDY * LDX);
        const int vr = v - vz * (LDY * LDX);
        const int vy = vr / LDX;
        const int vx = vr - vy * LDX;
        const int gz = clamp0(tbz + vz, D - 1);
        const int gy = clamp0(tby + vy, H - 1);
        const int gx = clamp0(tbx + vx, W - 1);
        const int gvox = (gz * H + gy) * W + gx;
        s_win[v * 4 + ((c + v) & 3)] = xbase[(size_t)gvox * 4 + c];
    }

    // ---- phase 1: per-task coords + weights + miss classification ----
    for (int t = tid; t < NTASK; t += TPB_MAIN) {
        const int tp = t & 31;
        const int ks = t >> 5;
        const int pz = tp >> 4, py = (tp >> 2) & 3, px = tp & 3;
        const int oz = oz0 + pz, oy = oy0 + py, ox = ox0 + px;
        const int n  = (oz * H + oy) * W + ox;
        const int kz = ks / 9;
        const int kr = ks - kz * 9;
        const int ky = kr / 3;
        const int kx = kr - ky * 3;

        const float offz = offb[(size_t)(ks * 3 + 0) * N + n];
        const float offy = offb[(size_t)(ks * 3 + 1) * N + n];
        const float offx = offb[(size_t)(ks * 3 + 2) * N + n];

        const float z  = (float)(oz - 1 + kz) + offz;
        const float y  = (float)(oy - 1 + ky) + offy;
        const float xx = (float)(ox - 1 + kx) + offx;
        const float zf = floorf(z), yf = floorf(y), xf = floorf(xx);
        const float fz = z - zf, fy = y - yf, fx = xx - xf;
        const int z0 = (int)zf, y0 = (int)yf, x0 = (int)xf;

        h8v cw8;
        #pragma unroll
        for (int cr = 0; cr < 8; ++cr) {
            const int cz = cr >> 2, cy = (cr >> 1) & 1, cx = cr & 1;
            const int iz = z0 + cz, iy = y0 + cy, ix = x0 + cx;
            const bool vd = ((unsigned)iz < (unsigned)D) &&
                            ((unsigned)iy < (unsigned)H) &&
                            ((unsigned)ix < (unsigned)W);
            const float wz = cz ? fz : 1.0f - fz;
            const float wy = cy ? fy : 1.0f - fy;
            const float wx = cx ? fx : 1.0f - fx;
            cw8[cr] = (_Float16)(vd ? (wz * wy * wx) : 0.0f);
        }

        const int rz = z0 - tbz, ry = y0 - tby, rx = x0 - tbx;
        const bool in = ((unsigned)rz <= (unsigned)(LDZ - 2)) &&
                        ((unsigned)ry <= (unsigned)(LDY - 2)) &&
                        ((unsigned)rx <= (unsigned)(LDX - 2));
        const int rzc = clamp0(rz, LDZ - 2);
        const int ryc = clamp0(ry, LDY - 2);
        const int rxc = clamp0(rx, LDX - 2);
        const int rv0 = (rzc * LDY + ryc) * LDX + rxc;

        unsigned mslot = 0xFFu;
        if (!in) {
            const int sl = atomicAdd(&s_cnt, 1);
            if (sl < CAP) { mslot = (unsigned)sl; s_mlist[sl] = (unsigned short)t; }
            else          { mslot = 0xFEu; }
        }
        s_cw[t]   = cw8;
        s_meta[t] = (unsigned)rv0 | (mslot << 16);
    }
    __syncthreads();

    // ---- phase 2: compacted miss gathers (lane-packed) ----
    const int cnt = min(s_cnt, CAP);
    for (int i = tid; i < cnt * 4; i += TPB_MAIN) {
        const int s  = i >> 2;
        const int q2 = i & 3;
        const int t  = s_mlist[s];
        const int tp = t & 31;
        const int ks = t >> 5;
        const int pz = tp >> 4, py = (tp >> 2) & 3, px = tp & 3;
        const int oz = oz0 + pz, oy = oy0 + py, ox = ox0 + px;
        const int n  = (oz * H + oy) * W + ox;
        const int kz = ks / 9;
        const int kr = ks - kz * 9;
        const int ky = kr / 3;
        const int kx = kr - ky * 3;

        const float offz = offb[(size_t)(ks * 3 + 0) * N + n];
        const float offy = offb[(size_t)(ks * 3 + 1) * N + n];
        const float offx = offb[(size_t)(ks * 3 + 2) * N + n];
        const int z0 = (int)floorf((float)(oz - 1 + kz) + offz);
        const int y0 = (int)floorf((float)(oy - 1 + ky) + offy);
        const int x0 = (int)floorf((float)(ox - 1 + kx) + offx);

        const h8v cw8 = s_cw[t];
        h8v acc = splat8h((_Float16)0.0f);
        #pragma unroll
        for (int cr = 0; cr < 8; ++cr) {
            const int cz = cr >> 2, cy = (cr >> 1) & 1, cx = cr & 1;
            const int izc = clamp0(z0 + cz, D - 1);
            const int iyc = clamp0(y0 + cy, H - 1);
            const int ixc = clamp0(x0 + cx, W - 1);
            const int gvox = (izc * H + iyc) * W + ixc;
            acc += xbase[(size_t)gvox * 4 + q2] * splat8h(cw8[cr]);
        }
        s_mval[s * 4 + q2] = acc;
    }
    __syncthreads();

    // ---- phase 3: branch-free k-loop + MFMA ----
    const int phat = pg * 16 + p;
    const int pz = phat >> 4, py = (phat >> 2) & 3, px = phat & 3;
    const int oz = oz0 + pz, oy = oy0 + py, ox = ox0 + px;
    const int n  = (oz * H + oy) * W + ox;

    const int k0 = kh ? 14 : 0;
    const int k1 = kh ? 27 : 14;

    f32x4 acc[4];
    #pragma unroll
    for (int ot = 0; ot < 4; ++ot) acc[ot] = (f32x4){0.f, 0.f, 0.f, 0.f};

    #pragma unroll 1
    for (int ks = k0; ks < k1; ++ks) {
        // A-fragments first: VMEM latency hides under the LDS work below
        h8v afr[4];
        #pragma unroll
        for (int ot = 0; ot < 4; ++ot)
            afr[ot] = wbase[(ot * 27 + ks) * 64 + lane];

        const int t = ks * 32 + phat;
        const h8v      cw8  = s_cw[t];
        const unsigned meta = s_meta[t];
        const int      rv0  = (int)(meta & 1023u);
        const unsigned ms   = (meta >> 16) & 0xFFu;

        h8v v8[8];
        #pragma unroll
        for (int cr = 0; cr < 8; ++cr) {
            const int rv = rv0 + (cr >> 2) * (LDY * LDX)
                         + ((cr >> 1) & 1) * LDX + (cr & 1);
            v8[cr] = s_win[rv * 4 + ((q + rv) & 3)];
        }
        h8v bfr = splat8h((_Float16)0.0f);
        #pragma unroll
        for (int cr = 0; cr < 8; ++cr)
            bfr += v8[cr] * splat8h(cw8[cr]);

        if (ms < 0xFEu)
            bfr = s_mval[(int)ms * 4 + q];      // masked LDS select (rare lanes)

        if (ms == 0xFEu) {                      // overflow: ~never
            const int kz = ks / 9;
            const int kr = ks - kz * 9;
            const int ky = kr / 3;
            const int kx = kr - ky * 3;
            const float offz = offb[(size_t)(ks * 3 + 0) * N + n];
            const float offy = offb[(size_t)(ks * 3 + 1) * N + n];
            const float offx = offb[(size_t)(ks * 3 + 2) * N + n];
            const int z0 = (int)floorf((float)(oz - 1 + kz) + offz);
            const int y0 = (int)floorf((float)(oy - 1 + ky) + offy);
            const int x0 = (int)floorf((float)(ox - 1 + kx) + offx);
            h8v a2 = splat8h((_Float16)0.0f);
            #pragma unroll
            for (int cr = 0; cr < 8; ++cr) {
                const int cz = cr >> 2, cy = (cr >> 1) & 1, cx = cr & 1;
                const int izc = clamp0(z0 + cz, D - 1);
                const int iyc = clamp0(y0 + cy, H - 1);
                const int ixc = clamp0(x0 + cx, W - 1);
                const int gvox = (izc * H + iyc) * W + ixc;
                a2 += xbase[(size_t)gvox * 4 + q] * splat8h(cw8[cr]);
            }
            bfr = a2;
        }

        #pragma unroll
        for (int ot = 0; ot < 4; ++ot)
            acc[ot] = __builtin_amdgcn_mfma_f32_16x16x32_f16(afr[ot], bfr,
                                                             acc[ot], 0, 0, 0);
    }

    // ---- cross-wave K reduction (reuse s_cw region) ----
    __syncthreads();
    float4* s_red = reinterpret_cast<float4*>(s_cw);   // 8 KB used
    if (kh == 1) {
        float4* dst = &s_red[((size_t)pg * 64 + lane) * 4];
        #pragma unroll
        for (int ot = 0; ot < 4; ++ot)
            dst[ot] = make_float4(acc[ot][0], acc[ot][1], acc[ot][2], acc[ot][3]);
    }
    __syncthreads();
    if (kh == 0) {
        const float4* src = &s_red[((size_t)pg * 64 + lane) * 4];
        #pragma unroll
        for (int ot = 0; ot < 4; ++ot) {
            const float4 tv = src[ot];
            acc[ot][0] += tv.x; acc[ot][1] += tv.y;
            acc[ot][2] += tv.z; acc[ot][3] += tv.w;
        }
        #pragma unroll
        for (int ot = 0; ot < 4; ++ot) {
            #pragma unroll
            for (int r = 0; r < 4; ++r) {
                const int o = ot * 16 + q * 4 + r;
                out[((size_t)(b * CO + o)) * N + n] = acc[ot][r] + bias[o];
            }
        }
    }
}

extern "C" void kernel_launch(void* const* d_in, const int* in_sizes, int n_in,
                              void* d_out, int out_size, void* d_ws, size_t ws_size,
                              hipStream_t stream) {
    const float* x    = (const float*)d_in[0];
    const float* off  = (const float*)d_in[1];
    const float* wgt  = (const float*)d_in[2];
    const float* bias = (const float*)d_in[3];
    float* out = (float*)d_out;

    _Float16* xT = (_Float16*)d_ws;                        // 1,769,472 B
    _Float16* wp = (_Float16*)((char*)d_ws + 1769472);     //   110,592 B

    prep_fused<<<PREPX_BLKS + PREPW_BLKS, 256, 0, stream>>>(x, wgt, xT, wp);
    deform_main<<<NBLK, TPB_MAIN, 0, stream>>>(off, xT, wp, bias, out);
}